// Round 2
// baseline (401.617 us; speedup 1.0000x reference)
//
#include <hip/hip_runtime.h>

// CTC batch loss, B=256, T=512, C=256, U=64. One 64-lane wave per batch.
// Lane l owns extended states 2l (blank) and 2l+1 (label l); lane 63 also
// owns state 128. Linear-domain forward recurrence with periodic power-of-2
// rescaling; full y_pred rows staged global->LDS via async global_load_lds
// (16-slot ring, explicit vmcnt throttling), LDS->reg gather 4 steps ahead.

constexpr int B = 256, T = 512, C = 256, U = 64;
constexpr int NS = 16;                 // LDS ring slots (16 KB)
#define EPSF 1e-7f

typedef const void __attribute__((address_space(1)))* gas1;
typedef void __attribute__((address_space(3)))* las3;

__global__ __launch_bounds__(64) void ctc_kernel(const int* __restrict__ y_true,
                                                 const float* __restrict__ y_pred,
                                                 float* __restrict__ out) {
    __shared__ float lds[NS * C];
    const int b = blockIdx.x;
    const int lane = threadIdx.x;
    const int label = y_true[b * U + lane];
    const int label_prev = __shfl_up(label, 1);
    const bool skip_ok = (lane > 0) && (label != label_prev);
    const float* rowp = y_pred + (size_t)b * (T * C);

    // Prologue: issue rows 0..NS-2 into slots 0..NS-2 (15 loads in flight).
#pragma unroll
    for (int r = 0; r < NS - 1; ++r) {
        const float* gp = rowp + r * C + lane * 4;   // 16 B per lane = full 1KB row
        __builtin_amdgcn_global_load_lds((gas1)gp, (las3)&lds[r * C], 16, 0, 0);
    }

    // Warm the LDS->reg pipe with rows 0..3. vmcnt(11): 4 oldest of 15 done.
    float plab[4], pblk[4];
    __builtin_amdgcn_s_waitcnt(0x0F7B);
#pragma unroll
    for (int r = 0; r < 4; ++r) {
        plab[r] = *(volatile const float*)&lds[r * C + label];
        pblk[r] = *(volatile const float*)&lds[r * C + (C - 1)];
    }

    float a_even = 0.f, a_odd = 0.f, a_top = 0.f;
    int esum = 0;

    for (int t0 = 0; t0 < T; t0 += 8) {
#pragma unroll
        for (int i = 0; i < 8; ++i) {
            const int t = t0 + i;
            // Issue row t+15 into slot (t+15)%16 (clamped dup rows in tail
            // keep vmcnt accounting uniform; they land in already-dead slots).
            int rt = t + NS - 1; rt = rt < T ? rt : T - 1;
            const float* gp = rowp + (size_t)rt * C + lane * 4;
            __builtin_amdgcn_global_load_lds((gas1)gp, (las3)&lds[(rt & (NS - 1)) * C],
                                             16, 0, 0);
            // 16 loads outstanding; wait until <=11 -> rows t..t+4 arrived.
            __builtin_amdgcn_s_waitcnt(0x0F7B);

            const float pb = pblk[i & 3] + EPSF;     // row t (read 4 iters ago)
            const float pl = plab[i & 3] + EPSF;
            int rn = t + 4; rn = rn < T ? rn : T - 1;
            const int sl = (rn & (NS - 1)) * C;
            plab[i & 3] = *(volatile const float*)&lds[sl + label];
            pblk[i & 3] = *(volatile const float*)&lds[sl + (C - 1)];

            // prev_odd = alpha[2l-1]; lane 0 gets 0 (alpha[-1]) via bound_ctrl.
            const float po = __int_as_float(__builtin_amdgcn_update_dpp(
                0, __float_as_int(a_odd), 0x138, 0xf, 0xf, true)); // wave_shr:1
            const float skp = skip_ok ? po : 0.f;
            const float ne = (a_even + po) * pb;
            const float no = (a_odd + a_even + skp) * pl;
            const float nt = (a_top + a_odd) * pb;
            a_even = ne; a_odd = no; a_top = nt;
            if (i == 0 && t0 == 0) {                 // t = 0: alpha0 init
                a_even = (lane == 0) ? pb : 0.f;
                a_odd  = (lane == 0) ? pl : 0.f;
                a_top  = 0.f;
            }
        }
        // Wave-uniform power-of-two rescale every 8 steps (DPP max-reduce).
        float m = fmaxf(fmaxf(a_even, a_odd), a_top);
#define RED(ctrl) { float x_ = __int_as_float(__builtin_amdgcn_update_dpp( \
            0, __float_as_int(m), ctrl, 0xf, 0xf, true)); m = fmaxf(m, x_); }
        RED(0x111) RED(0x112) RED(0x114) RED(0x118)  // row_shr 1,2,4,8
        RED(0x142) RED(0x143)                        // row_bcast15, row_bcast31
        const float mx = __int_as_float(
            __builtin_amdgcn_readlane(__float_as_int(m), 63));
        const int e = (__float_as_int(mx) >> 23) & 0xff;
        const float scale = __int_as_float((254 - e) << 23);  // 2^(127-e)
        a_even *= scale; a_odd *= scale; a_top *= scale;
        esum += e - 127;
    }
    // loss = -ln(alpha[128] + alpha[127]) in true scale.
    if (lane == 63)
        out[b] = -logf(a_top + a_odd) - (float)esum * 0.69314718055994531f;
}

extern "C" void kernel_launch(void* const* d_in, const int* in_sizes, int n_in,
                              void* d_out, int out_size, void* d_ws, size_t ws_size,
                              hipStream_t stream) {
    const int* y_true   = (const int*)d_in[0];
    const float* y_pred = (const float*)d_in[1];
    float* out = (float*)d_out;
    hipLaunchKernelGGL(ctc_kernel, dim3(B), dim3(64), 0, stream,
                       y_true, y_pred, out);
}

// Round 4
// 202.057 us; speedup vs baseline: 1.9876x; 1.9876x over previous
//
#include <hip/hip_runtime.h>

// CTC batch loss (keras ctc_batch_cost), B=256, T=512, C=256, U=64.
// One 64-lane wave per batch. Lane l owns extended states 2l (blank) and
// 2l+1 (label l); lane 63 also owns state 128 (its s-1 neighbor is its own
// odd register). Linear-domain forward recurrence, wave-uniform power-of-2
// rescale every 8 steps targeting 2^60 (large tail headroom). Data path:
// per-lane global gathers, chunked register double-buffering (16 steps per
// chunk, next chunk's 32 loads issued before computing current chunk;
// compile-time buffer alternation so all buffers live in VGPRs).

constexpr int B = 256, T = 512, C = 256, U = 64;
constexpr int CH = 16;
#define EPSF 1e-7f

__device__ __forceinline__ float dpp_wave_shr1(float x) {
    // alpha[2l-1]: previous lane's a_odd; lane 0 gets 0 (bound_ctrl).
    return __int_as_float(__builtin_amdgcn_update_dpp(
        0, __float_as_int(x), 0x138, 0xf, 0xf, true));
}

// Load chunk c (t = 1 + c*CH + i) into named register arrays.
#define LOAD_CHUNK(LA, BL, cidx)                                          \
    {                                                                     \
        const int c_ = (cidx);                                            \
        _Pragma("unroll")                                                 \
        for (int i = 0; i < CH; ++i) {                                    \
            int t = 1 + c_ * CH + i;                                      \
            t = t < T ? t : T - 1;                                        \
            LA[i] = labp[(size_t)t * C];                                  \
            BL[i] = blkp[(size_t)t * C];                                  \
        }                                                                 \
    }

#define DPPMAX(ctrl)                                                      \
    {                                                                     \
        float x_ = __int_as_float(__builtin_amdgcn_update_dpp(            \
            0, __float_as_int(m_), (ctrl), 0xf, 0xf, true));              \
        m_ = fmaxf(m_, x_);                                               \
    }

#define RESCALE()                                                         \
    {                                                                     \
        float m_ = fmaxf(fmaxf(a_even, a_odd), a_top);                    \
        DPPMAX(0x111) DPPMAX(0x112) DPPMAX(0x114) DPPMAX(0x118)           \
        DPPMAX(0x142) DPPMAX(0x143)                                       \
        const float mx_ = __int_as_float(                                 \
            __builtin_amdgcn_readlane(__float_as_int(m_), 63));           \
        int e_ = (__float_as_int(mx_) >> 23) & 0xff;                      \
        int k_ = 187 - e_;                                                \
        k_ = k_ > 127 ? 127 : k_;                                         \
        const float s_ = __int_as_float((k_ + 127) << 23);                \
        a_even *= s_; a_odd *= s_; a_top *= s_;                           \
        esum += k_;                                                       \
    }

#define COMP_CHUNK(LA, BL, cidx)                                          \
    {                                                                     \
        const int c_ = (cidx);                                            \
        _Pragma("unroll")                                                 \
        for (int i = 0; i < CH; ++i) {                                    \
            const int t = 1 + c_ * CH + i;                                \
            if (t < T) {                                                  \
                const float pb = BL[i] + EPSF;                            \
                const float pl = LA[i] + EPSF;                            \
                const float po = dpp_wave_shr1(a_odd);                    \
                const float skp = skip_ok ? po : 0.f;                     \
                const float ne = (a_even + po) * pb;                      \
                const float no = (a_odd + a_even + skp) * pl;             \
                const float nt = (a_top + a_odd) * pb;                    \
                a_even = ne; a_odd = no; a_top = nt;                      \
                if ((t & 7) == 0) RESCALE();                              \
            }                                                             \
        }                                                                 \
    }

__global__ __launch_bounds__(64) void ctc_kernel(const int* __restrict__ y_true,
                                                 const float* __restrict__ y_pred,
                                                 float* __restrict__ out) {
    const int b = blockIdx.x;
    const int lane = threadIdx.x;
    const int label = y_true[b * U + lane];
    const int label_prev = __shfl_up(label, 1);
    const bool skip_ok = (lane > 0) && (label != label_prev);
    const float* __restrict__ rowp = y_pred + (size_t)b * (T * C);
    const float* __restrict__ labp = rowp + label;       // + t*C per step
    const float* __restrict__ blkp = rowp + (C - 1);     // wave-uniform addr

    // t = 0 init (linear domain; unreachable states = 0).
    float a_even, a_odd, a_top;
    {
        const float pb = blkp[0] + EPSF;
        const float pl = labp[0] + EPSF;
        a_even = (lane == 0) ? pb : 0.f;
        a_odd  = (lane == 0) ? pl : 0.f;
        a_top  = 0.f;
    }
    int esum = 0;  // stored = true * 2^esum

    float la0[CH], bl0[CH], la1[CH], bl1[CH];
    LOAD_CHUNK(la0, bl0, 0);                 // chunk 0: t = 1..16

    for (int c2 = 0; c2 < 16; ++c2) {
        const int c = 2 * c2;
        LOAD_CHUNK(la1, bl1, c + 1);         // prefetch next chunk
        __builtin_amdgcn_sched_barrier(0);
        COMP_CHUNK(la0, bl0, c);
        if (c2 < 15) LOAD_CHUNK(la0, bl0, c + 2);
        __builtin_amdgcn_sched_barrier(0);
        COMP_CHUNK(la1, bl1, c + 1);
    }

    // loss = -ln(alpha[128] + alpha[127]); true = stored * 2^-esum
    if (lane == 63)
        out[b] = -logf(a_top + a_odd) + (float)esum * 0.69314718055994531f;
}

extern "C" void kernel_launch(void* const* d_in, const int* in_sizes, int n_in,
                              void* d_out, int out_size, void* d_ws, size_t ws_size,
                              hipStream_t stream) {
    const int* y_true   = (const int*)d_in[0];
    const float* y_pred = (const float*)d_in[1];
    float* out = (float*)d_out;
    hipLaunchKernelGGL(ctc_kernel, dim3(B), dim3(64), 0, stream,
                       y_true, y_pred, out);
}